// Round 3
// baseline (577.496 us; speedup 1.0000x reference)
//
#include <hip/hip_runtime.h>
#include <hip/hip_bf16.h>
#include <math.h>

#define MDIM  128
#define FEAT  8256      // 128*129/2
#define HID   1651
#define HIDP  1664      // 13*128, zero-padded
#define BATCH 4096
#define BK    64
#define KT_TOTAL 129    // FEAT / BK
#define NZ    2
#define KT_PER 64       // z=0: 64 iters, z=1: 65 iters

using f32x4  = __attribute__((ext_vector_type(4))) float;
using bf16x8 = __attribute__((ext_vector_type(8))) __bf16;

__device__ __forceinline__ void gload_lds16(const void* g, void* l) {
    __builtin_amdgcn_global_load_lds(
        (const __attribute__((address_space(1))) void*)g,
        (__attribute__((address_space(3))) void*)l,
        16, 0, 0);
}

__device__ __forceinline__ int row_off(int i) { return (i * (257 - i)) >> 1; }

// ---------------------------------------------------------------------------
// Kernel 1: gather triu(sim) -> X bf16 [BATCH, FEAT]
// One block per batch row. Coalesced float4 read of the full 128x128 matrix
// into LDS (bf16), then triu-gather from LDS, bf16x8 coalesced writes.
// ---------------------------------------------------------------------------
__global__ void __launch_bounds__(256)
pack_x_kernel(const float* __restrict__ sim,
              __hip_bfloat16* __restrict__ X) {
    __shared__ __hip_bfloat16 s[MDIM * MDIM];   // 32 KB
    const int b = blockIdx.x;
    const int t = threadIdx.x;

    const f32x4* src = (const f32x4*)(sim + ((long long)b << 14));
#pragma unroll
    for (int it = 0; it < 16; ++it) {
        const int idx = it * 256 + t;           // float4 index, 4096 total
        const f32x4 v = src[idx];
        __hip_bfloat16* d = &s[idx * 4];
        d[0] = __float2bfloat16(v[0]);
        d[1] = __float2bfloat16(v[1]);
        d[2] = __float2bfloat16(v[2]);
        d[3] = __float2bfloat16(v[3]);
    }
    __syncthreads();

    __hip_bfloat16* dst = X + (long long)b * FEAT;
#pragma unroll
    for (int it = 0; it < 5; ++it) {
        const int w = it * 256 + t;             // bf16x8 chunk index
        if (w < FEAT / 8) {
            const int f0 = w * 8;
            int i = (int)((257.0f - sqrtf(66049.0f - 8.0f * (float)f0)) * 0.5f);
            i = i < 0 ? 0 : (i > 127 ? 127 : i);
            while (i < 127 && row_off(i + 1) <= f0) ++i;
            while (i > 0 && row_off(i) > f0) --i;
            int j = i + (f0 - row_off(i));
            __align__(16) __hip_bfloat16 tmp[8];
#pragma unroll
            for (int e = 0; e < 8; ++e) {
                if (j > 127) { ++i; j = i; }
                tmp[e] = s[i * MDIM + j];
                ++j;
            }
            *(bf16x8*)(dst + f0) = *(const bf16x8*)tmp;
        }
    }
}

// ---------------------------------------------------------------------------
// Kernel 2: W1 fp32 [HID, FEAT] -> bf16 [HIDP, FEAT], rows >= HID zeroed.
// grid (5, HIDP): no integer division, vectorized both sides.
// ---------------------------------------------------------------------------
__global__ void __launch_bounds__(256)
conv_w1_kernel(const float* __restrict__ W1,
               __hip_bfloat16* __restrict__ W1p) {
    const int w = blockIdx.x * 256 + threadIdx.x;
    if (w >= FEAT / 8) return;
    const int n  = blockIdx.y;
    const int f0 = w * 8;
    __align__(16) __hip_bfloat16 tmp[8];
    if (n < HID) {
        const float* src = W1 + (long long)n * FEAT + f0;
        const f32x4 a = *(const f32x4*)src;
        const f32x4 c = *(const f32x4*)(src + 4);
#pragma unroll
        for (int e = 0; e < 4; ++e) {
            tmp[e]     = __float2bfloat16(a[e]);
            tmp[e + 4] = __float2bfloat16(c[e]);
        }
    } else {
#pragma unroll
        for (int e = 0; e < 8; ++e) tmp[e] = __float2bfloat16(0.0f);
    }
    *(bf16x8*)(W1p + (long long)n * FEAT + f0) = *(const bf16x8*)tmp;
}

// ---------------------------------------------------------------------------
// Kernel 3: split-K (NZ=2) GEMM, 128x128 tile, BK=64, XOR-swizzled LDS
// (0 bank conflicts, verified round 2). Partials stored as plain bf16
// stores into Cz[z][BATCH][HIDP] -- no atomics, no cross-XCD RMW.
// ---------------------------------------------------------------------------
__global__ void __launch_bounds__(256, 2)
gemm_split_kernel(const __hip_bfloat16* __restrict__ X,
                  const __hip_bfloat16* __restrict__ W1p,
                  __hip_bfloat16* __restrict__ Cz) {
    __shared__ __align__(16) __hip_bfloat16 lds_a[128 * BK];
    __shared__ __align__(16) __hip_bfloat16 lds_b[128 * BK];

    const int t    = threadIdx.x;
    const int wave = t >> 6;
    const int lane = t & 63;
    const int bm   = blockIdx.x;
    const int bn   = blockIdx.y;
    const int z    = blockIdx.z;
    const int wm   = wave >> 1;
    const int wn   = wave & 1;
    const int lr   = lane & 15;
    const int lq   = lane >> 4;

    f32x4 acc[4][4];
#pragma unroll
    for (int i = 0; i < 4; ++i)
#pragma unroll
        for (int j = 0; j < 4; ++j)
            acc[i][j] = (f32x4){0.f, 0.f, 0.f, 0.f};

    const int kt0 = z * KT_PER;
    const int nkt = (z == NZ - 1) ? (KT_TOTAL - KT_PER * (NZ - 1)) : KT_PER;

    const int swc = (t & 7) ^ ((t >> 3) & 7);   // swizzled global source chunk
    const __hip_bfloat16* gA =
        X + (long long)(bm * 128 + (t >> 3)) * FEAT + swc * 8 + kt0 * BK;
    const __hip_bfloat16* gB =
        W1p + (long long)(bn * 128 + (t >> 3)) * FEAT + swc * 8 + kt0 * BK;
    __hip_bfloat16* lA = lds_a + wave * 512;
    __hip_bfloat16* lB = lds_b + wave * 512;

    for (int kt = 0; kt < nkt; ++kt) {
#pragma unroll
        for (int s = 0; s < 4; ++s) {
            gload_lds16(gA + (long long)s * 32 * FEAT, lA + s * 2048);
            gload_lds16(gB + (long long)s * 32 * FEAT, lB + s * 2048);
        }
        gA += BK;
        gB += BK;
        __syncthreads();

#pragma unroll
        for (int ks = 0; ks < 2; ++ks) {
            bf16x8 af[4], bfr[4];
#pragma unroll
            for (int i = 0; i < 4; ++i) {
                const int ra = wm * 64 + i * 16 + lr;
                const int rb = wn * 64 + i * 16 + lr;
                const int kc = ks * 4 + lq;
                af[i]  = *(const bf16x8*)&lds_a[(ra * 8 + (kc ^ (lr & 7))) * 8];
                bfr[i] = *(const bf16x8*)&lds_b[(rb * 8 + (kc ^ (lr & 7))) * 8];
            }
#pragma unroll
            for (int i = 0; i < 4; ++i)
#pragma unroll
                for (int j = 0; j < 4; ++j)
                    acc[i][j] = __builtin_amdgcn_mfma_f32_16x16x32_bf16(
                        af[i], bfr[j], acc[i][j], 0, 0, 0);
        }
        __syncthreads();
    }

    // plain bf16 stores of this z-slice's partial pre-activations
    __hip_bfloat16* cz = Cz + ((long long)z * BATCH + bm * 128) * HIDP
                            + bn * 128 + wn * 64;
#pragma unroll
    for (int i = 0; i < 4; ++i)
#pragma unroll
        for (int r = 0; r < 4; ++r) {
            const int ml = wm * 64 + i * 16 + lq * 4 + r;
#pragma unroll
            for (int j = 0; j < 4; ++j)
                cz[(long long)ml * HIDP + j * 16 + lr] =
                    __float2bfloat16(acc[i][j][r]);
        }
}

// ---------------------------------------------------------------------------
// Kernel 4: out[b] = sigmoid(b2 + sum_n relu(Cz0[b,n]+Cz1[b,n]+b1[n])*W2[n])
// one block per batch row
// ---------------------------------------------------------------------------
__global__ void __launch_bounds__(256)
epilogue_kernel(const __hip_bfloat16* __restrict__ Cz,
                const float* __restrict__ b1,
                const float* __restrict__ W2,
                const float* __restrict__ b2,
                float* __restrict__ out) {
    const int b = blockIdx.x;
    const int t = threadIdx.x;
    float sum = 0.0f;
    const bf16x8* r0 = (const bf16x8*)(Cz + (long long)b * HIDP);
    const bf16x8* r1 = (const bf16x8*)(Cz + ((long long)BATCH + b) * HIDP);
    if (t < HIDP / 8) {   // 208 active threads, one pass
        const bf16x8 a = r0[t];
        const bf16x8 c = r1[t];
#pragma unroll
        for (int e = 0; e < 8; ++e) {
            const int n = t * 8 + e;
            if (n < HID) {
                const float v = (float)a[e] + (float)c[e] + b1[n];
                sum += fmaxf(v, 0.0f) * W2[n];
            }
        }
    }
    sum += __shfl_xor(sum, 1);
    sum += __shfl_xor(sum, 2);
    sum += __shfl_xor(sum, 4);
    sum += __shfl_xor(sum, 8);
    sum += __shfl_xor(sum, 16);
    sum += __shfl_xor(sum, 32);
    __shared__ float wsum[4];
    if ((t & 63) == 0) wsum[t >> 6] = sum;
    __syncthreads();
    if (t == 0) {
        const float s = wsum[0] + wsum[1] + wsum[2] + wsum[3];
        out[b] = 1.0f / (1.0f + expf(-(s + b2[0])));
    }
}

extern "C" void kernel_launch(void* const* d_in, const int* in_sizes, int n_in,
                              void* d_out, int out_size, void* d_ws, size_t ws_size,
                              hipStream_t stream) {
    const float* sim = (const float*)d_in[0];
    const float* W1  = (const float*)d_in[1];
    const float* b1  = (const float*)d_in[2];
    const float* W2  = (const float*)d_in[3];
    const float* b2  = (const float*)d_in[4];
    float* out = (float*)d_out;

    char* ws = (char*)d_ws;
    const long long X_OFF   = 0;
    const long long W1P_OFF = 67633152LL;              // BATCH*FEAT*2
    const long long CZ_OFF  = W1P_OFF + 27475968LL;    // + HIDP*FEAT*2
    // CZ bytes: NZ*BATCH*HIDP*2 = 27,262,976; total = 122,372,096 (== proven ws bound)
    __hip_bfloat16* X   = (__hip_bfloat16*)(ws + X_OFF);
    __hip_bfloat16* W1p = (__hip_bfloat16*)(ws + W1P_OFF);
    __hip_bfloat16* Cz  = (__hip_bfloat16*)(ws + CZ_OFF);

    pack_x_kernel<<<BATCH, 256, 0, stream>>>(sim, X);
    {
        dim3 grid((FEAT / 8 + 255) / 256, HIDP);       // (5, 1664)
        conv_w1_kernel<<<grid, 256, 0, stream>>>(W1, W1p);
    }
    {
        dim3 grid(BATCH / 128, HIDP / 128, NZ);        // (32, 13, 2)
        gemm_split_kernel<<<grid, 256, 0, stream>>>(X, W1p, Cz);
    }
    epilogue_kernel<<<BATCH, 256, 0, stream>>>(Cz, b1, W2, b2, out);
}

// Round 4
// 503.615 us; speedup vs baseline: 1.1467x; 1.1467x over previous
//
#include <hip/hip_runtime.h>
#include <hip/hip_bf16.h>
#include <math.h>

#define MDIM  128
#define FEAT  8256      // 128*129/2 (elements == bytes in fp8)
#define HID   1651
#define HIDP  1664      // 13*128, zero-padded
#define BATCH 4096
#define BK    64
#define KT_TOTAL 129    // FEAT / BK
#define NZ    2
#define KT_PER 64       // z=0: 64 iters, z=1: 65 iters
#define W1SCALE 8192.0f
#define W1INV   (1.0f / 8192.0f)

using f32x4  = __attribute__((ext_vector_type(4))) float;
using bf16x8 = __attribute__((ext_vector_type(8))) __bf16;
typedef long long i64;

__device__ __forceinline__ void gload_lds16(const void* g, void* l) {
    __builtin_amdgcn_global_load_lds(
        (const __attribute__((address_space(1))) void*)g,
        (__attribute__((address_space(3))) void*)l,
        16, 0, 0);
}

__device__ __forceinline__ int row_off(int i) { return (i * (257 - i)) >> 1; }

// pack 8 floats -> 8 fp8 e4m3 bytes (two ints)
__device__ __forceinline__ void pack8_fp8(const float* f, int* o) {
    int lo = __builtin_amdgcn_cvt_pk_fp8_f32(f[0], f[1], 0, false);
    lo     = __builtin_amdgcn_cvt_pk_fp8_f32(f[2], f[3], lo, true);
    int hi = __builtin_amdgcn_cvt_pk_fp8_f32(f[4], f[5], 0, false);
    hi     = __builtin_amdgcn_cvt_pk_fp8_f32(f[6], f[7], hi, true);
    o[0] = lo; o[1] = hi;
}

// ---------------------------------------------------------------------------
// Kernel 1: gather triu(sim) -> X fp8 [BATCH, FEAT]. Direct global reads of
// ONLY the triu region (~135 MB, not 256 MB). One block per batch row.
// ---------------------------------------------------------------------------
__global__ void __launch_bounds__(256)
pack_x_kernel(const float* __restrict__ sim, char* __restrict__ X) {
    const int b = blockIdx.x;
    const int t = threadIdx.x;
    const float* srow = sim + ((long long)b << 14);
    char* dst = X + (long long)b * FEAT;
#pragma unroll
    for (int it = 0; it < 5; ++it) {
        const int w = it * 256 + t;
        if (w < FEAT / 8) {
            const int f0 = w * 8;
            int i = (int)((257.0f - sqrtf(66049.0f - 8.0f * (float)f0)) * 0.5f);
            i = i < 0 ? 0 : (i > 127 ? 127 : i);
            while (i < 127 && row_off(i + 1) <= f0) ++i;
            while (i > 0 && row_off(i) > f0) --i;
            int j = i + (f0 - row_off(i));
            float v[8];
#pragma unroll
            for (int e = 0; e < 8; ++e) {
                if (j > 127) { ++i; j = i; }
                v[e] = srow[i * MDIM + j];
                ++j;
            }
            int o[2];
            pack8_fp8(v, o);
            *(int2*)(dst + f0) = make_int2(o[0], o[1]);
        }
    }
}

// ---------------------------------------------------------------------------
// Kernel 2: W1 fp32 [HID, FEAT] * 8192 -> fp8 [HIDP, FEAT], rows >= HID zero.
// ---------------------------------------------------------------------------
__global__ void __launch_bounds__(256)
conv_w1_kernel(const float* __restrict__ W1, char* __restrict__ W1p) {
    const int w = blockIdx.x * 256 + threadIdx.x;
    if (w >= FEAT / 8) return;
    const int n  = blockIdx.y;
    const int f0 = w * 8;
    int o[2];
    if (n < HID) {
        const float* src = W1 + (long long)n * FEAT + f0;
        const f32x4 a = *(const f32x4*)src;
        const f32x4 c = *(const f32x4*)(src + 4);
        float v[8];
#pragma unroll
        for (int e = 0; e < 4; ++e) {
            v[e]     = a[e] * W1SCALE;
            v[e + 4] = c[e] * W1SCALE;
        }
        pack8_fp8(v, o);
    } else {
        o[0] = 0; o[1] = 0;
    }
    *(int2*)(W1p + (long long)n * FEAT + f0) = make_int2(o[0], o[1]);
}

// ---------------------------------------------------------------------------
// Kernel 3: split-K (NZ=2) fp8 GEMM, 128x128 tile, BK=64.
// LDS: 64 B/row, 4 x 16B chunks; physical chunk = logical ^ sw(row),
// sw(r) = (r&3)^((r>>2)&3)  (<=2-way bank aliasing on b64 reads = free).
// Store side achieves this by swizzling the per-lane GLOBAL source chunk.
// bf16 partial stores, no atomics.
// ---------------------------------------------------------------------------
__global__ void __launch_bounds__(256, 4)
gemm_split_kernel(const char* __restrict__ X,
                  const char* __restrict__ W1p,
                  __hip_bfloat16* __restrict__ Cz) {
    __shared__ __align__(16) char lds_a[128 * BK];   // 8 KB
    __shared__ __align__(16) char lds_b[128 * BK];   // 8 KB

    const int t    = threadIdx.x;
    const int wave = t >> 6;
    const int lane = t & 63;
    const int bm   = blockIdx.x;
    const int bn   = blockIdx.y;
    const int z    = blockIdx.z;
    const int wm   = wave >> 1;
    const int wn   = wave & 1;
    const int lr   = lane & 15;
    const int lq   = lane >> 4;

    f32x4 acc[4][4];
#pragma unroll
    for (int i = 0; i < 4; ++i)
#pragma unroll
        for (int j = 0; j < 4; ++j)
            acc[i][j] = (f32x4){0.f, 0.f, 0.f, 0.f};

    const int kt0 = z * KT_PER;
    const int nkt = (z == NZ - 1) ? (KT_TOTAL - KT_PER * (NZ - 1)) : KT_PER;

    // staging: issue s covers rows s*64 + (t>>2); 4 chunks (t&3) per row.
    // swizzled source chunk: (t&3) ^ sw(row); sw(row) = ((t>>2)&3)^((t>>4)&3)
    const int swst = (t & 3) ^ ((t >> 2) & 3) ^ ((t >> 4) & 3);
    const char* gA = X + (long long)(bm * 128 + (t >> 2)) * FEAT
                       + kt0 * BK + swst * 16;
    const char* gB = W1p + (long long)(bn * 128 + (t >> 2)) * FEAT
                         + kt0 * BK + swst * 16;
    char* lA = lds_a + wave * 1024;   // + lane*16 by HW
    char* lB = lds_b + wave * 1024;

    const int ksw = (lq & 1) * 8;     // byte offset within 16B chunk
    const int cl  = lq >> 1;          // logical chunk low bit source

    for (int kt = 0; kt < nkt; ++kt) {
#pragma unroll
        for (int s = 0; s < 2; ++s) {
            gload_lds16(gA + (long long)s * 64 * FEAT, lA + s * 4096);
            gload_lds16(gB + (long long)s * 64 * FEAT, lB + s * 4096);
        }
        gA += BK;
        gB += BK;
        __syncthreads();

#pragma unroll
        for (int ks = 0; ks < 2; ++ks) {
            i64 av[4], bv[4];
#pragma unroll
            for (int i = 0; i < 4; ++i) {
                const int ra = wm * 64 + i * 16 + lr;
                const int rb = wn * 64 + i * 16 + lr;
                const int swa = (ra & 3) ^ ((ra >> 2) & 3);
                const int swb = (rb & 3) ^ ((rb >> 2) & 3);
                const int pa = ((ks * 2 + cl) ^ swa);
                const int pb = ((ks * 2 + cl) ^ swb);
                av[i] = *(const i64*)(lds_a + ra * 64 + pa * 16 + ksw);
                bv[i] = *(const i64*)(lds_b + rb * 64 + pb * 16 + ksw);
            }
#pragma unroll
            for (int i = 0; i < 4; ++i)
#pragma unroll
                for (int j = 0; j < 4; ++j)
                    acc[i][j] = __builtin_amdgcn_mfma_f32_16x16x32_fp8_fp8(
                        av[i], bv[j], acc[i][j], 0, 0, 0);
        }
        __syncthreads();
    }

    // plain bf16 stores of this z-slice's partial (scaled) pre-activations
    __hip_bfloat16* cz = Cz + ((long long)z * BATCH + bm * 128) * HIDP
                            + bn * 128 + wn * 64;
#pragma unroll
    for (int i = 0; i < 4; ++i)
#pragma unroll
        for (int r = 0; r < 4; ++r) {
            const int ml = wm * 64 + i * 16 + lq * 4 + r;
#pragma unroll
            for (int j = 0; j < 4; ++j)
                cz[(long long)ml * HIDP + j * 16 + lr] =
                    __float2bfloat16(acc[i][j][r]);
        }
}

// ---------------------------------------------------------------------------
// Kernel 4: out[b] = sigmoid(b2 + sum_n relu((Cz0+Cz1)*W1INV + b1[n]) * W2[n])
// ---------------------------------------------------------------------------
__global__ void __launch_bounds__(256)
epilogue_kernel(const __hip_bfloat16* __restrict__ Cz,
                const float* __restrict__ b1,
                const float* __restrict__ W2,
                const float* __restrict__ b2,
                float* __restrict__ out) {
    const int b = blockIdx.x;
    const int t = threadIdx.x;
    float sum = 0.0f;
    const bf16x8* r0 = (const bf16x8*)(Cz + (long long)b * HIDP);
    const bf16x8* r1 = (const bf16x8*)(Cz + ((long long)BATCH + b) * HIDP);
    if (t < HIDP / 8) {   // 208 active threads, one pass
        const bf16x8 a = r0[t];
        const bf16x8 c = r1[t];
#pragma unroll
        for (int e = 0; e < 8; ++e) {
            const int n = t * 8 + e;
            if (n < HID) {
                const float v = ((float)a[e] + (float)c[e]) * W1INV + b1[n];
                sum += fmaxf(v, 0.0f) * W2[n];
            }
        }
    }
    sum += __shfl_xor(sum, 1);
    sum += __shfl_xor(sum, 2);
    sum += __shfl_xor(sum, 4);
    sum += __shfl_xor(sum, 8);
    sum += __shfl_xor(sum, 16);
    sum += __shfl_xor(sum, 32);
    __shared__ float wsum[4];
    if ((t & 63) == 0) wsum[t >> 6] = sum;
    __syncthreads();
    if (t == 0) {
        const float s = wsum[0] + wsum[1] + wsum[2] + wsum[3];
        out[b] = 1.0f / (1.0f + expf(-(s + b2[0])));
    }
}

extern "C" void kernel_launch(void* const* d_in, const int* in_sizes, int n_in,
                              void* d_out, int out_size, void* d_ws, size_t ws_size,
                              hipStream_t stream) {
    const float* sim = (const float*)d_in[0];
    const float* W1  = (const float*)d_in[1];
    const float* b1  = (const float*)d_in[2];
    const float* W2  = (const float*)d_in[3];
    const float* b2  = (const float*)d_in[4];
    float* out = (float*)d_out;

    char* ws = (char*)d_ws;
    const long long X_OFF   = 0;                       // 33,816,576 B
    const long long W1P_OFF = (long long)BATCH * FEAT; // fp8: elems == bytes
    const long long CZ_OFF  = W1P_OFF + (long long)HIDP * FEAT;  // +13,737,984
    // Cz: NZ*BATCH*HIDP*2 = 27,262,976 B; total 74,817,536 < proven ws bound
    char*           Xf8  = ws + X_OFF;
    char*           W1f8 = ws + W1P_OFF;
    __hip_bfloat16* Cz   = (__hip_bfloat16*)(ws + CZ_OFF);

    pack_x_kernel<<<BATCH, 256, 0, stream>>>(sim, Xf8);
    {
        dim3 grid((FEAT / 8 + 255) / 256, HIDP);       // (5, 1664)
        conv_w1_kernel<<<grid, 256, 0, stream>>>(W1, W1f8);
    }
    {
        dim3 grid(BATCH / 128, HIDP / 128, NZ);        // (32, 13, 2)
        gemm_split_kernel<<<grid, 256, 0, stream>>>(Xf8, W1f8, Cz);
    }
    epilogue_kernel<<<BATCH, 256, 0, stream>>>(Cz, b1, W2, b2, out);
}